// Round 1
// baseline (227.651 us; speedup 1.0000x reference)
//
#include <hip/hip_runtime.h>

// Problem constants (from reference setup_inputs)
constexpr int B = 4, C = 96, H = 192, W = 320;
constexpr int HW      = H * W;       // 61440 floats per (b,c) plane
constexpr int HW4     = HW / 4;      // 15360 float4 per (b,c) plane
constexpr int OUT_CH  = 81;

// ---- phase 1 tiling ----
constexpr int GROUPS  = 8;           // channel groups per block
constexpr int CPG     = C / GROUPS;  // 12 channels per group
constexpr int SPB     = 32;          // spatial float4 per block
constexpr int TOTAL_S4  = B * HW4;   // 61440 corr float4s  -> 1920 blocks

// ---- phase 2 tiling ----
constexpr int OCH     = 27;              // out-channels per block
constexpr int OCB     = OUT_CH / OCH;    // 3 o-chunks
constexpr int S4PB    = 256;             // spatial f4 per phase2 block
constexpr int SCHUNKS = HW4 / S4PB;      // 60 spatial chunks per (b)
constexpr int TOTAL_OUT4 = B * OUT_CH * HW4; // for fallback sizing

typedef float f32x4 __attribute__((ext_vector_type(4)));

// ---------------- Phase 1: corr map (reads-dominated) ----------------
// Block = 256 threads = 32 spatial-float4 x 8 channel-groups -> 1920 blocks
// (7.5 blocks/CU, 30 waves/CU). Each thread accumulates dot & |f1|-sum over
// its 12 channels in explicit 4-pair load batches (8 float4 loads in flight,
// VGPR-budgeted <=64 so full occupancy is allowed). LDS-reduce across the
// 8 groups; g==0 threads write the 983 KB corr map with regular stores
// (stays in L2/L3 for phase 2).
#define ACC(X, Y)                                                     \
    d.x = fmaf((X).x, (Y).x, d.x); d.y = fmaf((X).y, (Y).y, d.y);     \
    d.z = fmaf((X).z, (Y).z, d.z); d.w = fmaf((X).w, (Y).w, d.w);     \
    a.x += fabsf((X).x); a.y += fabsf((X).y);                         \
    a.z += fabsf((X).z); a.w += fabsf((X).w);

__global__ __launch_bounds__(256) void corr_phase1(
    const f32x4* __restrict__ f1,
    const f32x4* __restrict__ f2,
    f32x4* __restrict__ corr)
{
    __shared__ f32x4 sdot[GROUPS][SPB];
    __shared__ f32x4 sasum[GROUPS][SPB];

    const int s_local = threadIdx.x & (SPB - 1);
    const int g       = threadIdx.x >> 5;
    const int base4   = blockIdx.x * SPB;        // global spatial-f4 index
    const int b       = base4 / HW4;             // SPB divides HW4: no straddle
    const int splane  = (base4 - b * HW4) + s_local;

    const f32x4* __restrict__ p1 = f1 + ((size_t)(b * C + g * CPG)) * HW4 + splane;
    const f32x4* __restrict__ p2 = f2 + ((size_t)(b * C + g * CPG)) * HW4 + splane;

    f32x4 d = {0.f, 0.f, 0.f, 0.f};
    f32x4 a = {0.f, 0.f, 0.f, 0.f};

    // 3 batches of 4 channel-pairs. unroll 1 keeps VGPRs <= ~56 (full
    // occupancy); within a batch all 8 loads issue before any waitcnt.
#pragma unroll 1
    for (int j0 = 0; j0 < CPG; j0 += 4) {
        const f32x4 x0 = p1[(size_t)(j0 + 0) * HW4];
        const f32x4 x1 = p1[(size_t)(j0 + 1) * HW4];
        const f32x4 x2 = p1[(size_t)(j0 + 2) * HW4];
        const f32x4 x3 = p1[(size_t)(j0 + 3) * HW4];
        const f32x4 y0 = p2[(size_t)(j0 + 0) * HW4];
        const f32x4 y1 = p2[(size_t)(j0 + 1) * HW4];
        const f32x4 y2 = p2[(size_t)(j0 + 2) * HW4];
        const f32x4 y3 = p2[(size_t)(j0 + 3) * HW4];
        ACC(x0, y0)
        ACC(x1, y1)
        ACC(x2, y2)
        ACC(x3, y3)
    }

    sdot[g][s_local]  = d;
    sasum[g][s_local] = a;
    __syncthreads();

    if (g == 0) {
        f32x4 dt = sdot[0][s_local];
        f32x4 at = sasum[0][s_local];
#pragma unroll
        for (int k = 1; k < GROUPS; ++k) {
            const f32x4 dk = sdot[k][s_local];
            const f32x4 ak = sasum[k][s_local];
            dt.x += dk.x; dt.y += dk.y; dt.z += dk.z; dt.w += dk.w;
            at.x += ak.x; at.y += ak.y; at.z += ak.z; at.w += ak.w;
        }
        const float inv_c = 1.0f / (float)C;
        f32x4 r;
        r.x = (at.x > 0.1f) ? dt.x * inv_c : 0.0f;
        r.y = (at.y > 0.1f) ? dt.y * inv_c : 0.0f;
        r.z = (at.z > 0.1f) ? dt.z * inv_c : 0.0f;
        r.w = (at.w > 0.1f) ? dt.w * inv_c : 0.0f;
        corr[base4 + s_local] = r;   // regular store: stays cached for phase 2
    }
}

// ---------------- Phase 2: broadcast (writes-dominated) ----------------
// All 81 output channels are identical, so each thread reads its corr f32x4
// ONCE and issues 27 independent NT stores (81 split 3 ways for grid size).
// Removes 78 MB of redundant L2 corr re-reads and the per-thread division;
// stores are fire-and-forget so the kernel is purely write-BW-bound.
// Grid = 4 * 60 * 3 = 720 blocks (~2.8/CU).
__global__ __launch_bounds__(256) void corr_phase2(
    const f32x4* __restrict__ corr,
    f32x4* __restrict__ out)
{
    const int bid = blockIdx.x;          // [0, B*SCHUNKS*OCB)
    const int oc  = bid % OCB;
    const int t   = bid / OCB;
    const int b   = t / SCHUNKS;
    const int sc  = t - b * SCHUNKS;
    const int s4  = sc * S4PB + (int)threadIdx.x;

    const f32x4 r = corr[(size_t)b * HW4 + s4];
    f32x4* __restrict__ po = out + ((size_t)(b * OUT_CH + oc * OCH)) * HW4 + s4;
#pragma unroll
    for (int o = 0; o < OCH; ++o)
        __builtin_nontemporal_store(r, po + (size_t)o * HW4);
}

// ---------------- Fallback (ws too small): single kernel ----------------
__global__ __launch_bounds__(256) void spike_corr_mono(
    const float* __restrict__ f1,
    const float* __restrict__ f2,
    float* __restrict__ out)
{
    const int idx = blockIdx.x * blockDim.x + threadIdx.x;
    const int b = idx / HW;
    const int s = idx - b * HW;
    const float* __restrict__ p1 = f1 + (size_t)b * C * HW + s;
    const float* __restrict__ p2 = f2 + (size_t)b * C * HW + s;
    float dot = 0.f, asum = 0.f;
#pragma unroll 16
    for (int c = 0; c < C; ++c) {
        const float a = p1[(size_t)c * HW];
        const float v = p2[(size_t)c * HW];
        dot = fmaf(a, v, dot);
        asum += fabsf(a);
    }
    const float r = (asum > 0.1f) ? dot * (1.0f / (float)C) : 0.0f;
    float* __restrict__ po = out + (size_t)b * OUT_CH * HW + s;
#pragma unroll 1
    for (int o = 0; o < OUT_CH; ++o)
        __builtin_nontemporal_store(r, po + (size_t)o * HW);
}

extern "C" void kernel_launch(void* const* d_in, const int* in_sizes, int n_in,
                              void* d_out, int out_size, void* d_ws, size_t ws_size,
                              hipStream_t stream) {
    const size_t corr_bytes = (size_t)TOTAL_S4 * sizeof(f32x4);  // 983,040 B

    if (ws_size >= corr_bytes) {
        const f32x4* f1 = (const f32x4*)d_in[0];
        const f32x4* f2 = (const f32x4*)d_in[1];
        f32x4* corr = (f32x4*)d_ws;
        f32x4* out  = (f32x4*)d_out;

        corr_phase1<<<TOTAL_S4 / SPB, 256, 0, stream>>>(f1, f2, corr);       // 1920 blocks
        corr_phase2<<<B * SCHUNKS * OCB, 256, 0, stream>>>(corr, out);       // 720 blocks
    } else {
        const float* f1 = (const float*)d_in[0];
        const float* f2 = (const float*)d_in[1];
        float* out = (float*)d_out;
        spike_corr_mono<<<(B * HW) / 256, 256, 0, stream>>>(f1, f2, out);
    }
}